// Round 10
// baseline (33.429 us; speedup 1.0000x reference)
//
#include <hip/hip_runtime.h>
#include <math.h>

constexpr int NB    = 128;
constexpr int NPAIR = NB * (NB - 1) / 2;        // 8128
constexpr int NANG  = NB - 2;                   // 126
constexpr int NDIH  = NB - 3;                   // 125
constexpr int ROW   = NPAIR + NANG + 2 * NDIH;  // 8504

// Dense complementary-row pairing: rows off and 128-off together have exactly
// 128 pairs. Lane l computes dist(s4[l], s4[(l+off)&127]) — covers row off at
// pos l (when l+off<128) or row 128-off at pos l-(128-off) (when l+off>=128).
// Zero exec-mask waste, one conflict-free ds_read_b128 + one dense store/iter.
__global__ __launch_bounds__(1024, 8) void protein_feat_kernel(
        const float* __restrict__ data, float* __restrict__ out) {
    __shared__ float4 s4[NB];                    // (x,y,z,0) per bead
    const int b  = blockIdx.x;
    const int t  = threadIdx.x;                  // 0..1023
    const int tb = t & 127;                      // lane-in-group == bead index
    const int g  = t >> 7;                       // group 0..7 (wave-uniform)
    const float* src = data + (size_t)b * (NB * 3);

    if (t < NB)
        s4[t] = make_float4(src[3 * t], src[3 * t + 1], src[3 * t + 2], 0.0f);
    __syncthreads();

    float* orow = out + (size_t)b * ROW;

    // Lane-local endpoint.
    const float4 p0 = s4[tb];

    // ---- Distances: group g handles off = 8g+1 .. 8g+8 (g=7 includes off=64,
    // which self-pairs: upper half duplicates lower half's writes, same value).
    #pragma unroll 2
    for (int m = 0; m < 8; ++m) {
        const int off = 8 * g + 1 + m;
        const int r2  = NB - off;                             // complementary row
        const int c1  = (off - 1) * (2 * NB - off) / 2;       // B(off)
        const int c2  = (r2 - 1) * (2 * NB - r2) / 2 - r2;    // B(128-off)-(128-off)
        float4 pj = s4[(tb + off) & (NB - 1)];                // rotated, conflict-free
        float dx = pj.x - p0.x;
        float dy = pj.y - p0.y;
        float dz = pj.z - p0.z;
        float d  = __builtin_amdgcn_sqrtf(dx * dx + dy * dy + dz * dz);
        const int base = (tb + off < NB) ? c1 : c2;           // one cndmask
        orow[base + tb] = d;                                  // dense segments
    }

    // ---- Angles (126) + dihedral cos (125) + dihedral sin (125): t<376 only.
    const int v = t;
    if (v < NANG + 2 * NDIH) {
        if (v < NANG) {
            int a = v;
            float4 q0 = s4[a], q1 = s4[a + 1], q2 = s4[a + 2];
            float a0x = q1.x - q0.x, a0y = q1.y - q0.y, a0z = q1.z - q0.z;
            float a1x = q2.x - q1.x, a1y = q2.y - q1.y, a1z = q2.z - q1.z;
            float d  = a0x * a1x + a0y * a1y + a0z * a1z;
            float r0 = rsqrtf(a0x * a0x + a0y * a0y + a0z * a0z);
            float r1 = rsqrtf(a1x * a1x + a1y * a1y + a1z * a1z);
            float c  = d * r0 * r1;
            c = fminf(1.0f, fmaxf(-1.0f, c));
            orow[NPAIR + a] = acosf(c);
        } else {
            int a = (v < NANG + NDIH) ? (v - NANG) : (v - NANG - NDIH);
            float4 q0 = s4[a], q1 = s4[a + 1], q2 = s4[a + 2], q3 = s4[a + 3];
            float e0x = q1.x - q0.x, e0y = q1.y - q0.y, e0z = q1.z - q0.z;
            float e1x = q2.x - q1.x, e1y = q2.y - q1.y, e1z = q2.z - q1.z;
            float e2x = q3.x - q2.x, e2y = q3.y - q2.y, e2z = q3.z - q2.z;
            float c0x = e0y * e1z - e0z * e1y;
            float c0y = e0z * e1x - e0x * e1z;
            float c0z = e0x * e1y - e0y * e1x;
            float c1x = e1y * e2z - e1z * e2y;
            float c1y = e1z * e2x - e1x * e2z;
            float c1z = e1x * e2y - e1y * e2x;
            float rn0 = rsqrtf(c0x * c0x + c0y * c0y + c0z * c0z);
            if (v < NANG + NDIH) {
                float d   = c0x * c1x + c0y * c1y + c0z * c1z;
                float rn1 = rsqrtf(c1x * c1x + c1y * c1y + c1z * c1z);
                orow[NPAIR + NANG + a] = d * rn0 * rn1;
            } else {
                float qx = c1y * e1z - c1z * e1y;   // plane = c1 x e1
                float qy = c1z * e1x - c1x * e1z;
                float qz = c1x * e1y - c1y * e1x;
                float d  = c0x * qx + c0y * qy + c0z * qz;
                float rp = rsqrtf(qx * qx + qy * qy + qz * qz);
                orow[NPAIR + NANG + NDIH + a] = d * rn0 * rp;
            }
        }
    }
}

extern "C" void kernel_launch(void* const* d_in, const int* in_sizes, int n_in,
                              void* d_out, int out_size, void* d_ws, size_t ws_size,
                              hipStream_t stream) {
    const float* data = (const float*)d_in[0];
    float* out = (float*)d_out;
    const int batch = in_sizes[0] / (NB * 3);   // 4096
    protein_feat_kernel<<<batch, 1024, 0, stream>>>(data, out);
}